// Round 14
// baseline (55.965 us; speedup 1.0000x reference)
//
#include <hip/hip_runtime.h>
#include <stdint.h>

#define BSZ 4096
#define LSEQ 1024

typedef _Float16 half8 __attribute__((ext_vector_type(8)));
typedef __fp16 fp16x2 __attribute__((ext_vector_type(2)));
typedef float f32x4 __attribute__((ext_vector_type(4)));

union S8 { int i[4]; half8 h; int4 q; };

__device__ __forceinline__ int pack_f16(float a, float b) {
    union { _Float16 h[2]; int i; } u;
    u.h[0] = (_Float16)a;          // v_cvt_f16_f32 (RNE)
    u.h[1] = (_Float16)b;
    return u.i;                    // v_pack_b32_f16
}
// RTZ pack then packed f16 relu: v_cvt_pkrtz_f16_f32 + v_pk_max_f16 (2 VALU)
__device__ __forceinline__ int relu_pkrtz(float a, float b) {
    fp16x2 h = __builtin_amdgcn_cvt_pkrtz(a, b);
    h = __builtin_elementwise_max(h, (fp16x2)0.f);
    union { fp16x2 v; int i; } u;
    u.v = h;
    return u.i;
}
// (a,b) -> hi dword [f16(b)|f16(a)], lo dword [f16(b-bh)|f16(a-ah)]
__device__ __forceinline__ void split_pair_f16(float a, float b, int& dh, int& dl) {
    _Float16 ah = (_Float16)a, bh = (_Float16)b;
    float al = a - (float)ah, bl = b - (float)bh;
    union { _Float16 h[2]; int i; } uh, ul;
    uh.h[0] = ah; uh.h[1] = bh;
    ul.h[0] = (_Float16)al; ul.h[1] = (_Float16)bl;
    dh = uh.i; dl = ul.i;
}
__device__ __forceinline__ f32x4 MFMA(half8 a, half8 b, f32x4 c) {
    return __builtin_amdgcn_mfma_f32_16x16x32_f16(a, b, c, 0, 0, 0);
}

// ws layout (int units):
//   int4 slots 0..13   : A fragments [f][lane]   (14*64*4 = 3584 ints)
//   f32x4 slots 14..17 : bias1 C-frags [mt][lane]
//   f32x4 slots 18..19 : bias2 C-frags [mt2][lane]
//   f32x4 slot  20     : bias3 C-frag  [lane]
//   WS_EMBH + app      : embedding hi dword (f16 e0,e1)
//   WS_EMBL + app      : embedding lo dword
//   WS_EMBR + i        : raw normalized embedding floats [10][2]
#define WS_EMBH 5376
#define WS_EMBL 5392
#define WS_EMBR 5408

__global__ void sp_prep(const float* __restrict__ emb,
                        const float* __restrict__ fW1, const float* __restrict__ fb1,
                        const float* __restrict__ fW2, const float* __restrict__ fb2,
                        const float* __restrict__ fW3, const float* __restrict__ fb3,
                        int* __restrict__ ws)
{
    const int lane = threadIdx.x;          // 64 threads, 1 wave
    const int L = lane & 15, g = lane >> 4;
    int4* wf = (int4*)ws;
    f32x4* bp = (f32x4*)ws;

    // ---- A1: one frag per mt; A 2-term f16 packed along K ----
    // B1 supplies (all lanes): [d_eh, d_l, d_el, 0]; A zero for g>=2 masks k>=16.
    #pragma unroll
    for (int mt = 0; mt < 4; ++mt) {
        int j1 = ((mt >> 1) << 5) + ((L >> 2) << 3) + ((mt & 1) << 2) + (L & 3);
        float wv[4];
        _Float16 ah[4]; float alv[4];
        #pragma unroll
        for (int c = 0; c < 4; ++c) {
            wv[c] = (j1 < 50) ? fW1[c * 50 + j1] : 0.f;
            ah[c] = (_Float16)wv[c];
            alv[c] = wv[c] - (float)ah[c];
        }
        _Float16 v[8];
        #pragma unroll
        for (int e = 0; e < 8; ++e) {
            _Float16 x = (_Float16)0.f;
            if (g == 0) {
                if (e < 4) x = ah[e];
                else if (e < 6) x = ah[e - 4];
            } else if (g == 1) {
                if (e < 4) x = (_Float16)alv[e];
                else if (e < 6) x = (_Float16)alv[e - 4];
            }
            v[e] = x;
        }
        S8 F;
        #pragma unroll
        for (int d = 0; d < 4; ++d) {
            union { _Float16 h[2]; int i; } u;
            u.h[0] = v[2 * d]; u.h[1] = v[2 * d + 1];
            F.i[d] = u.i;
        }
        wf[mt * 64 + lane] = F.q;
    }

    // ---- A2 Ah/Al frags (sigma2 row permutation; f16 2-term) ----
    #pragma unroll
    for (int kt = 0; kt < 2; ++kt) {
        #pragma unroll
        for (int mt2 = 0; mt2 < 2; ++mt2) {
            int j2 = ((L >> 2) << 3) + (mt2 << 2) + (L & 3);
            float w[8];
            #pragma unroll
            for (int r = 0; r < 8; ++r) {
                int j1v = kt * 32 + 8 * g + r;
                w[r] = (j1v < 50 && j2 < 25) ? fW2[j1v * 25 + j2] : 0.f;
            }
            S8 H, Lo;
            #pragma unroll
            for (int d = 0; d < 4; ++d) split_pair_f16(w[2*d], w[2*d+1], H.i[d], Lo.i[d]);
            wf[(4 + kt * 2 + mt2) * 64 + lane] = H.q;
            wf[(8 + kt * 2 + mt2) * 64 + lane] = Lo.q;
        }
    }

    // ---- A3 Ah/Al frags ----
    {
        int m = L;
        float w[8];
        #pragma unroll
        for (int r = 0; r < 8; ++r) {
            int j2v = 8 * g + r;
            w[r] = (j2v < 25 && m < 5) ? fW3[j2v * 5 + m] : 0.f;
        }
        S8 H, Lo;
        #pragma unroll
        for (int d = 0; d < 4; ++d) split_pair_f16(w[2*d], w[2*d+1], H.i[d], Lo.i[d]);
        wf[12 * 64 + lane] = H.q;
        wf[13 * 64 + lane] = Lo.q;
    }

    // ---- bias C-fragments (C/D row = 4g+r, col = L) ----
    #pragma unroll
    for (int mt = 0; mt < 4; ++mt) {
        f32x4 bv;
        #pragma unroll
        for (int r = 0; r < 4; ++r) {
            int j1 = ((mt >> 1) << 5) + 8 * g + ((mt & 1) << 2) + r;
            bv[r] = (j1 < 50) ? fb1[j1] : 0.f;
        }
        bp[(14 + mt) * 64 + lane] = bv;
    }
    #pragma unroll
    for (int mt2 = 0; mt2 < 2; ++mt2) {
        f32x4 bv;
        #pragma unroll
        for (int r = 0; r < 4; ++r) {
            int j2 = 8 * g + 4 * mt2 + r;
            bv[r] = (j2 < 25) ? fb2[j2] : 0.f;
        }
        bp[(18 + mt2) * 64 + lane] = bv;
    }
    {
        f32x4 bv;
        #pragma unroll
        for (int r = 0; r < 4; ++r) {
            int m = 4 * g + r;
            bv[r] = (m < 5) ? fb3[m] : 0.f;
        }
        bp[20 * 64 + lane] = bv;
    }

    // ---- renormalized embedding: raw floats + f16 hi/lo dwords ----
    if (lane < 10) {
        float a0 = emb[2 * lane], a1 = emb[2 * lane + 1];
        float n = sqrtf(a0 * a0 + a1 * a1);
        float s = fminf(1.f, 1.f / fmaxf(n, 1e-7f));
        float e0 = a0 * s, e1 = a1 * s;
        int dh, dl;
        split_pair_f16(e0, e1, dh, dl);
        ws[WS_EMBH + lane] = dh;
        ws[WS_EMBL + lane] = dl;
        ((float*)ws)[WS_EMBR + 2 * lane] = e0;
        ((float*)ws)[WS_EMBR + 2 * lane + 1] = e1;
    }
}

__global__ __launch_bounds__(256, 4) void sp_main(
    const float* __restrict__ x_features,
    const float* __restrict__ features,
    const int* __restrict__ ws,
    const float* __restrict__ rW1, const float* __restrict__ rb1,
    const float* __restrict__ rW2, const float* __restrict__ rb2,
    const float* __restrict__ rW3, const float* __restrict__ rb3,
    float* __restrict__ out)
{
    __shared__ int2 embhl[16];
    __shared__ float embr[20];
    __shared__ int4 bseq[LSEQ + 4];   // staged B1 frags, idx = p + (p>>8) bank-stagger
    __shared__ float redS[4][5], redM[4][5];
    __shared__ float hhs[14];
    __shared__ float r1buf[50];

    const int t = threadIdx.x;
    const int b = blockIdx.x;
    const int lane = t & 63;
    const int wid = t >> 6;
    const int L = lane & 15;

    // ---- load prepacked A fragments + bias C-frags (L2-broadcast) ----
    const int4* wf = (const int4*)ws;
    const f32x4* bp = (const f32x4*)ws;
    S8 A1[4], A2H[4], A2L[4], A3H, A3L;
    #pragma unroll
    for (int f = 0; f < 4; ++f)  A1[f].q  = wf[f * 64 + lane];
    #pragma unroll
    for (int f = 0; f < 4; ++f)  A2H[f].q = wf[(4 + f) * 64 + lane];
    #pragma unroll
    for (int f = 0; f < 4; ++f)  A2L[f].q = wf[(8 + f) * 64 + lane];
    A3H.q = wf[12 * 64 + lane];
    A3L.q = wf[13 * 64 + lane];
    f32x4 b1c[4], b2c[2], b3c;
    #pragma unroll
    for (int f = 0; f < 4; ++f) b1c[f] = bp[(14 + f) * 64 + lane];
    b2c[0] = bp[18 * 64 + lane];
    b2c[1] = bp[19 * 64 + lane];
    b3c = bp[20 * 64 + lane];

    // ---- PIN all persistent fragments in VGPRs ----
    // Opaque asm becomes the def point: the compiler can no longer
    // rematerialize these via in-loop L2 reloads (VGPR_Count 64 < the 84
    // persistent regs proved it was doing exactly that).
    #pragma unroll
    for (int f = 0; f < 4; ++f) {
        asm volatile("" : "+v"(A1[f].h));
        asm volatile("" : "+v"(A2H[f].h));
        asm volatile("" : "+v"(A2L[f].h));
        asm volatile("" : "+v"(b1c[f]));
    }
    asm volatile("" : "+v"(A3H.h));
    asm volatile("" : "+v"(A3L.h));
    asm volatile("" : "+v"(b2c[0]));
    asm volatile("" : "+v"(b2c[1]));
    asm volatile("" : "+v"(b3c));

    if (t < 16) { embhl[t] = make_int2(ws[WS_EMBH + t], ws[WS_EMBL + t]); }
    if (t < 20) embr[t] = ((const float*)ws)[WS_EMBR + t];
    __syncthreads();

    // ---- stage the block's inputs as ready-to-use B1 int4 frags ----
    // thread t handles positions {t, t+256, t+512, t+768}: scalar loads stay
    // coalesced (256B/instr) and ds_write_b128 lane-stride is 16B -> conflict-free.
    const float* f0 = features + (size_t)b * (3 * LSEQ);
    #pragma unroll
    for (int j = 0; j < 4; ++j) {
        const int p = t + 256 * j;
        float av = f0[p];
        float bv = f0[LSEQ + p];
        float cv = f0[2 * LSEQ + p];
        int2 e = embhl[(int)av];
        bseq[p + j] = make_int4(e.x, pack_f16(bv, cv), e.y, 0);   // p>>8 == j
    }
    __syncthreads();

    float rs[4] = {0.f, 0.f, 0.f, 0.f};
    float rm[4] = {-3.4e38f, -3.4e38f, -3.4e38f, -3.4e38f};

    const int lbase = wid * 257 + L;        // includes +wid bank-stagger

    // register prefetch of B1 (one ds_read_b128 ahead)
    S8 B1c;
    B1c.q = bseq[lbase];

    #pragma unroll 2
    for (int it = 0; it < 16; ++it) {
        S8 B1n;
        B1n.q = bseq[lbase + ((it + 1) & 15) * 16];   // wraps on last iter

        // GEMM1: 4 MFMAs (A 2-term packed along K), bias in C
        f32x4 h1[4];
        #pragma unroll
        for (int mt = 0; mt < 4; ++mt)
            h1[mt] = MFMA(A1[mt].h, B1c.h, b1c[mt]);

        // B2 frags: RTZ pack + packed relu (2 ops/dword), sigma1 D->k alignment
        S8 B20, B21;
        B20.i[0] = relu_pkrtz(h1[0][0], h1[0][1]);
        B20.i[1] = relu_pkrtz(h1[0][2], h1[0][3]);
        B20.i[2] = relu_pkrtz(h1[1][0], h1[1][1]);
        B20.i[3] = relu_pkrtz(h1[1][2], h1[1][3]);
        B21.i[0] = relu_pkrtz(h1[2][0], h1[2][1]);
        B21.i[1] = relu_pkrtz(h1[2][2], h1[2][3]);
        B21.i[2] = relu_pkrtz(h1[3][0], h1[3][1]);
        B21.i[3] = relu_pkrtz(h1[3][2], h1[3][3]);

        // GEMM2: 8 MFMAs (Ah+Al per kt), bias in C
        f32x4 h2[2];
        #pragma unroll
        for (int mt2 = 0; mt2 < 2; ++mt2) {
            f32x4 acc = b2c[mt2];
            acc = MFMA(A2H[mt2].h,     B20.h, acc);
            acc = MFMA(A2L[mt2].h,     B20.h, acc);
            acc = MFMA(A2H[2 + mt2].h, B21.h, acc);
            acc = MFMA(A2L[2 + mt2].h, B21.h, acc);
            h2[mt2] = acc;
        }

        // B3 frag: RTZ pack + packed relu
        S8 B3;
        B3.i[0] = relu_pkrtz(h2[0][0], h2[0][1]);
        B3.i[1] = relu_pkrtz(h2[0][2], h2[0][3]);
        B3.i[2] = relu_pkrtz(h2[1][0], h2[1][1]);
        B3.i[3] = relu_pkrtz(h2[1][2], h2[1][3]);

        // GEMM3: 2 MFMAs, bias in C
        f32x4 h3 = MFMA(A3H.h, B3.h, b3c);
        h3 = MFMA(A3L.h, B3.h, h3);

        #pragma unroll
        for (int r = 0; r < 4; ++r) {
            rs[r] += h3[r];
            rm[r] = fmaxf(rm[r], h3[r]);
        }

        B1c = B1n;
    }

    // ---- reduce over the 16 position-lanes within each 16-lane group ----
    #pragma unroll
    for (int off = 1; off <= 8; off <<= 1) {
        #pragma unroll
        for (int r = 0; r < 4; ++r) {
            rs[r] += __shfl_xor(rs[r], off);
            rm[r] = fmaxf(rm[r], __shfl_xor(rm[r], off));
        }
    }
    {
        const int kg = (lane >> 4);
        if (L == 0) {
            #pragma unroll
            for (int r = 0; r < 4; ++r) {
                int m = 4 * kg + r;
                if (m < 5) { redS[wid][m] = rs[r]; redM[wid][m] = rm[r]; }
            }
        }
    }
    __syncthreads();

    // ---- combine 4 waves + build hh[14] ----
    if (t < 5) {
        hhs[t] = (redS[0][t] + redS[1][t]) + (redS[2][t] + redS[3][t]);
    } else if (t < 10) {
        int m = t - 5;
        hhs[t] = fmaxf(fmaxf(redM[0][m], redM[1][m]), fmaxf(redM[2][m], redM[3][m]));
    } else if (t == 10) {
        int xa = (int)x_features[b * 3];
        hhs[10] = embr[2 * xa];
        hhs[11] = embr[2 * xa + 1];
        hhs[12] = x_features[b * 3 + 1];
        hhs[13] = x_features[b * 3 + 2];
    }
    __syncthreads();

    // ---- head MLP: 14 -> 50 -> 25 -> 1 (weights direct from L2) ----
    if (t < 50) {
        float acc = rb1[t];
        #pragma unroll
        for (int i = 0; i < 14; ++i) acc += hhs[i] * rW1[i * 50 + t];
        r1buf[t] = fmaxf(acc, 0.f);
    }
    __syncthreads();

    float oacc = 0.f;
    if (t < 25) {
        float acc = rb2[t];
        #pragma unroll
        for (int k = 0; k < 50; ++k) acc += r1buf[k] * rW2[k * 25 + t];
        oacc = fmaxf(acc, 0.f) * rW3[t];
    }
    if (t < 64) {
        #pragma unroll
        for (int off = 32; off > 0; off >>= 1) oacc += __shfl_down(oacc, off);
        if (t == 0) out[b] = oacc + rb3[0];
    }
}

extern "C" void kernel_launch(void* const* d_in, const int* in_sizes, int n_in,
                              void* d_out, int out_size, void* d_ws, size_t ws_size,
                              hipStream_t stream) {
    const float* x_features = (const float*)d_in[0];
    const float* features   = (const float*)d_in[1];
    // d_in[2] = lengths (dead in the math)
    const float* emb = (const float*)d_in[3];
    const float* fW1 = (const float*)d_in[4];
    const float* fb1 = (const float*)d_in[5];
    const float* fW2 = (const float*)d_in[6];
    const float* fb2 = (const float*)d_in[7];
    const float* fW3 = (const float*)d_in[8];
    const float* fb3 = (const float*)d_in[9];
    const float* rW1 = (const float*)d_in[10];
    const float* rb1 = (const float*)d_in[11];
    const float* rW2 = (const float*)d_in[12];
    const float* rb2 = (const float*)d_in[13];
    const float* rW3 = (const float*)d_in[14];
    const float* rb3 = (const float*)d_in[15];
    float* out = (float*)d_out;
    int* ws = (int*)d_ws;

    sp_prep<<<1, 64, 0, stream>>>(emb, fW1, fb1, fW2, fb2, fW3, fb3, ws);
    sp_main<<<BSZ, 256, 0, stream>>>(x_features, features, ws,
                                     rW1, rb1, rW2, rb2, rW3, rb3, out);
}